// Round 11
// baseline (364.169 us; speedup 1.0000x reference)
//
#include <hip/hip_runtime.h>

#define NNODES 25000
#define NEDGES 400000
#define HDIM   32
#define NHEADS 10
#define NCOLS  320          // HEADS*HDIM
#define NEG    0.2f
#define EPSV   1e-5f
#define NQ     40000        // NEDGES/10 edge-groups (16-row tiles, 10 real rows)
#define TPW    4            // tiles per wave
#define GRID_MAIN 1250      // 1250 blocks x 8 waves x 4 tiles = 40000

typedef __bf16 bf16x8 __attribute__((ext_vector_type(8)));
typedef float  f32x4  __attribute__((ext_vector_type(4)));

__device__ __forceinline__ float leaky_f(float v) { return fmaxf(v, NEG * v); }

__device__ __forceinline__ unsigned pk2(float a, float b) {
  unsigned short ua = __builtin_bit_cast(unsigned short, (__bf16)a);
  unsigned short ub = __builtin_bit_cast(unsigned short, (__bf16)b);
  return (unsigned)ua | ((unsigned)ub << 16);
}
__device__ __forceinline__ float bflo(unsigned p) {
  return __builtin_bit_cast(float, p << 16);
}
__device__ __forceinline__ float bfhi(unsigned p) {
  return __builtin_bit_cast(float, p & 0xffff0000u);
}
__device__ __forceinline__ bf16x8 cvt8(float4 a, float4 b) {
  bf16x8 r;
  r[0] = (__bf16)a.x; r[1] = (__bf16)a.y; r[2] = (__bf16)a.z; r[3] = (__bf16)a.w;
  r[4] = (__bf16)b.x; r[5] = (__bf16)b.y; r[6] = (__bf16)b.z; r[7] = (__bf16)b.w;
  return r;
}

// x += neighbor(x) on the VALU pipe via DPP mov. CTRL is a compile-time imm.
template <int CTRL>
__device__ __forceinline__ float dpp_add(float x) {
  const int xi = __builtin_bit_cast(int, x);
  const int y  = __builtin_amdgcn_update_dpp(0, xi, CTRL, 0xf, 0xf, false);
  return x + __builtin_bit_cast(float, y);
}
// All-lanes sum over each 16-lane row (same result on every lane of the row):
// xor1 (quad_perm[1,0,3,2]=0xB1), xor2 (quad_perm[2,3,0,1]=0x4E) make each
// 4-group uniform; then row_ror:4 (0x124) and row_ror:8 (0x128) add the other
// 4-groups (uniformity makes rotation equivalent to xor). Pure VALU, no DS.
// Verified passing in round 10.
__device__ __forceinline__ float bfly16(float x) {
  x = dpp_add<0xB1>(x);
  x = dpp_add<0x4E>(x);
  x = dpp_add<0x124>(x);
  x = dpp_add<0x128>(x);
  return x;
}

__global__ void agat_init_out(float* __restrict__ out, const float* __restrict__ bias) {
  int i = blockIdx.x * 256 + threadIdx.x;
  if (i < NNODES * HDIM) out[i] = bias[i & (HDIM - 1)];
}

// One wave owns one 16-row tile (10 edges + 6 zero pads) completely: all 20
// column slots (10 heads), softmax computed redundantly on ALL lanes, zero
// steady-state barriers.
// vs round-10 (353us, spilling at the forced 128-VGPR cap):
//   - pass 1 keeps leaky(lin_j) as packed-bf16 ljp[20][2] (round-4-verified math);
//     pass 2 is now PURE VALU (alpha-weighting + 2 shfl + atomic): -40 MFMA,
//     -40 ds_read_b128, -80 leaky per tile, and the frags die at pass-1 end so
//     true peak pressure ~115 VGPR -> under the 128 boundary (4 waves/SIMD).
//   - __launch_bounds__(512, 2): cap 256, so the allocator is never FORCED to
//     spill (round 10's FETCH 566MB was scratch traffic from the 128 cap).
// W^T LDS layout (verified conflict-free r7/r8/r10: SQ_LDS_BANK_CONFLICT==0):
//   (c,k) at byte c*128 + (((k>>3)^(c&7))<<4) + (k&7)*2, staged b128.
__global__ __launch_bounds__(512, 2) void agat_fused(
    const float* __restrict__ x,
    const int*   __restrict__ eidx,
    const float* __restrict__ ea,
    const float* __restrict__ W,
    const float* __restrict__ att,
    const float* __restrict__ gamma,
    const float* __restrict__ beta,
    const float* __restrict__ rmean,
    const float* __restrict__ rvar,
    float*       __restrict__ out)
{
  const int tid = threadIdx.x;
  const int w  = tid >> 6;   // wave 0..7
  const int l  = tid & 63;
  const int lq = l >> 4;     // quarter: k-slice (A/B), 4-row group (D)
  const int lr = l & 15;     // row (A), col-within-slot (B/D)

  __shared__ __align__(16) __bf16 wt[NCOLS * 64];   // 40960 B
  __shared__ unsigned attp[20 * 16];                // 1280 B

  // ---- stage W^T once: task = (c 0..319, ko 0..7), one b128 write each ----
  for (int task = tid; task < NCOLS * 8; task += 512) {
    const int c  = task >> 3;
    const int ko = task & 7;
    bf16x8 v;
#pragma unroll
    for (int j = 0; j < 8; ++j) v[j] = (__bf16)W[(8 * ko + j) * NCOLS + c];
    *(bf16x8*)((char*)wt + c * 128 + ((ko ^ (c & 7)) << 4)) = v;
  }
  // ---- stage packed att ----
  if (tid < 320) {
    const int t = tid >> 4, rr = tid & 15;
    const int h = t >> 1, cc = 16 * (t & 1) + rr;
    attp[tid] = pk2(att[h * 64 + cc], att[h * 64 + 32 + cc]);
  }

  // ---- GroupNorm affine -> SGPRs ----
  float gsS[NHEADS], gbS[NHEADS];
#pragma unroll
  for (int h = 0; h < NHEADS; ++h) {
    const float iv = rsqrtf(rvar[h] + EPSV);
    const float a  = iv * gamma[h];
    const float b  = beta[h] - rmean[h] * a;
    gsS[h] = __builtin_bit_cast(float, __builtin_amdgcn_readfirstlane(__builtin_bit_cast(int, a)));
    gbS[h] = __builtin_bit_cast(float, __builtin_amdgcn_readfirstlane(__builtin_bit_cast(int, b)));
  }

  __syncthreads();   // wt/attp visible; the only barrier

  const int wave_id = blockIdx.x * 8 + w;
  const f32x4 zero4 = {0.f, 0.f, 0.f, 0.f};
  const int sw = lr & 7;
  const char* base1 = (const char*)wt + lr * 128 + ((lq ^ sw) << 4);
  const char* base2 = (const char*)wt + lr * 128 + (((lq + 4) ^ sw) << 4);
  const unsigned* attb = attp + lr;

#pragma unroll 1
  for (int i = 0; i < TPW; ++i) {
    const int q = wave_id * TPW + i;   // tile id < 40000 by construction

    // ---- gather A-fragments (row lr, k-slice lq*8..+7) ----
    bf16x8 xif = (bf16x8)(__bf16)0.0f;
    bf16x8 xjf = (bf16x8)(__bf16)0.0f;
    bf16x8 eaf = (bf16x8)(__bf16)0.0f;
    if (lr < 10) {
      const int e  = q * 10 + lr;
      const int ri = eidx[e];
      const int ci = eidx[NEDGES + e];
      const float* xr = x + ri * HDIM + lq * 8;
      const float* xc = x + ci * HDIM + lq * 8;
      const float* ep = ea + e * HDIM + lq * 8;
      xif = cvt8(*(const float4*)xr, *(const float4*)(xr + 4));
      xjf = cvt8(*(const float4*)xc, *(const float4*)(xc + 4));
      eaf = cvt8(*(const float4*)ep, *(const float4*)(ep + 4));
    }

    // ---- pass 1: 20 slots, logit partials + packed leaky(lin_j) ----
    f32x4 zacc[NHEADS];
#pragma unroll
    for (int h = 0; h < NHEADS; ++h) zacc[h] = zero4;
    unsigned ljp[20][2];

#pragma unroll
    for (int t = 0; t < 20; ++t) {
      const bf16x8 w1 = *(const bf16x8*)(base1 + t * 2048);
      const bf16x8 w2 = *(const bf16x8*)(base2 + t * 2048);
      const unsigned ap = attb[t * 16];
      const f32x4 cc_ = __builtin_amdgcn_mfma_f32_16x16x32_bf16(eaf, w2, zero4, 0, 0, 0);
      const f32x4 ai  = __builtin_amdgcn_mfma_f32_16x16x32_bf16(xif, w1, cc_, 0, 0, 0);
      const f32x4 aj  = __builtin_amdgcn_mfma_f32_16x16x32_bf16(xjf, w1, cc_, 0, 0, 0);
      const float ti = bflo(ap);
      const float tj = bfhi(ap);
      const int h = t >> 1;
      float vj[4];
#pragma unroll
      for (int p = 0; p < 4; ++p) {
        const float vi = leaky_f(ai[p]);
        vj[p] = leaky_f(aj[p]);
        zacc[h][p] += vi * ti + vj[p] * tj;
      }
      ljp[t][0] = pk2(vj[0], vj[1]);
      ljp[t][1] = pk2(vj[2], vj[3]);
    }

    // ---- all-lanes 16-column reduction on the VALU pipe (DPP butterfly) ----
#pragma unroll
    for (int h = 0; h < NHEADS; ++h)
#pragma unroll
      for (int p = 0; p < 4; ++p)
        zacc[h][p] = bfly16(zacc[h][p]);

    // ---- GN affine + softmax per row (all lanes redundantly) ----
#pragma unroll
    for (int p = 0; p < 4; ++p) {
      float zb[NHEADS];
      float mx = -1e30f;
#pragma unroll
      for (int h = 0; h < NHEADS; ++h) {
        zb[h] = leaky_f(zacc[h][p]) * gsS[h] + gbS[h];
        mx = fmaxf(mx, zb[h]);
      }
      float ssum = 0.f;
#pragma unroll
      for (int h = 0; h < NHEADS; ++h) { zb[h] = __expf(zb[h] - mx); ssum += zb[h]; }
      const float inv = 1.0f / ssum;
#pragma unroll
      for (int h = 0; h < NHEADS; ++h) zacc[h][p] = zb[h] * inv;   // alpha
    }

    // ---- pass 2 (pure VALU): weight packed lj by alpha, group-sum, scatter ----
    int ng[5];
#pragma unroll
    for (int g = 0; g < 5; ++g)
      ng[g] = eidx[(2 * g + (lq >> 1)) * NQ + q];   // dest node for lane's slot

#pragma unroll
    for (int g = 0; g < 5; ++g) {
      float s4[4];
#pragma unroll
      for (int u = 0; u < 4; ++u) {
        const int t = 4 * g + u, h = t >> 1;
        float s = bflo(ljp[t][0]) * zacc[h][0] + bfhi(ljp[t][0]) * zacc[h][1]
                + bflo(ljp[t][1]) * zacc[h][2] + bfhi(ljp[t][1]) * zacc[h][3];
        s += __shfl_xor(s, 16, 64);
        s += __shfl_xor(s, 32, 64);    // all lanes hold the full 16-row sum
        s4[u] = s;
      }
      const float v01 = (lq & 1) ? s4[1] : s4[0];
      const float v23 = (lq & 1) ? s4[3] : s4[2];
      const float v   = (lq & 2) ? v23 : v01;       // slot t = 4g+lq
      atomicAdd(&out[ng[g] * HDIM + 16 * (lq & 1) + lr], 0.1f * v);
    }
  }
}

extern "C" void kernel_launch(void* const* d_in, const int* in_sizes, int n_in,
                              void* d_out, int out_size, void* d_ws, size_t ws_size,
                              hipStream_t stream) {
  const float* x     = (const float*)d_in[0];
  const int*   eidx  = (const int*)  d_in[1];
  const float* ea    = (const float*)d_in[2];
  const float* W     = (const float*)d_in[3];
  const float* att   = (const float*)d_in[4];
  const float* bias  = (const float*)d_in[5];
  const float* gamma = (const float*)d_in[6];
  const float* beta  = (const float*)d_in[7];
  const float* rmean = (const float*)d_in[8];
  const float* rvar  = (const float*)d_in[9];
  float* out = (float*)d_out;

  agat_init_out<<<(NNODES * HDIM + 255) / 256, 256, 0, stream>>>(out, bias);
  agat_fused<<<GRID_MAIN, 512, 0, stream>>>(x, eidx, ea, W, att, gamma, beta,
                                            rmean, rvar, out);
}